// Round 1
// baseline (127.733 us; speedup 1.0000x reference)
//
#include <hip/hip_runtime.h>
#include <math.h>

// ---------------------------------------------------------------------------
// MultiAttention, 3 launches (round-8: attn fused into FC GEMM):
//  1) conv: x->bf16, W->bf16^T, Vsum=0
//  2) gemm_qkv: 128x128 tile, 256 thr (768 blocks = 3/CU exact), BK=64,
//     global_load_lds + XOR-swizzled source, fused V col sums (atomics)
//  3) attn_fcln: per 32-row block: band attention (closed-form softmax)
//     computed straight into LDS as the GEMM A-operand (swizzled bf16),
//     then 32x512 FC GEMM, BK=64 B-only LDS double-buffer (128 KB) + ctx
//     (32 KB) = 160 KB LDS, one barrier/iter, DMA under MFMA chain;
//     epilogue residual(bf16) + LayerNorm. Kills the 16 MB ctx round-trip
//     and the attn dispatch.
// NOTE (R7 lesson): grids must be integral blocks/CU (>=2 where possible) —
// 1.5 blocks/CU tails and 1-block/CU mega-fusions both regressed.
// ---------------------------------------------------------------------------

typedef short     s8v  __attribute__((ext_vector_type(8)));   // 8 bf16
typedef float     f4v  __attribute__((ext_vector_type(4)));
typedef unsigned short us4v __attribute__((ext_vector_type(4)));
typedef unsigned short us8v __attribute__((ext_vector_type(8)));

__device__ __forceinline__ unsigned short f2b(float f) {
  union { float f; unsigned int u; } v; v.f = f;
  unsigned int u = v.u;
  return (unsigned short)((u + 0x7fffu + ((u >> 16) & 1u)) >> 16);  // RNE
}
__device__ __forceinline__ float b2f(unsigned short u) {
  union { unsigned int i; float f; } v; v.i = ((unsigned int)u) << 16;
  return v.f;
}
__device__ __forceinline__ void gload_lds16(const void* g, void* l) {
  __builtin_amdgcn_global_load_lds(
      (const __attribute__((address_space(1))) void*)g,
      (__attribute__((address_space(3))) void*)l, 16, 0, 0);
}

// ---------------- conv: x->bf16, W->bf16 transposed, Vsum=0 ----------------
__global__ __launch_bounds__(256) void conv_kernel(
    const float* __restrict__ x,
    const float* __restrict__ Wq, const float* __restrict__ Wk,
    const float* __restrict__ Wv, const float* __restrict__ Wfc,
    unsigned short* __restrict__ xb, unsigned short* __restrict__ Wt,
    float* __restrict__ Vsum) {
  __shared__ unsigned short tile[32][33];
  const int bid = blockIdx.x, t = threadIdx.x;
  if (bid < 4096) {
    const int i = bid * 256 + t;
    const float4 f = ((const float4*)x)[i];
    us4v o; o[0] = f2b(f.x); o[1] = f2b(f.y); o[2] = f2b(f.z); o[3] = f2b(f.w);
    ((us4v*)xb)[i] = o;
  } else if (bid < 5120) {
    const int id = bid - 4096;
    const int z = id >> 8, rem = id & 255;
    const int bx = rem & 15, by = rem >> 4;
    const float* W = (z == 0) ? Wq : (z == 1) ? Wk : (z == 2) ? Wv : Wfc;
    const int tx = t & 31, ty = t >> 5;
    const int n0 = bx * 32, k0 = by * 32;
    #pragma unroll
    for (int r = ty; r < 32; r += 8)
      tile[r][tx] = f2b(W[(size_t)(k0 + r) * 512 + n0 + tx]);
    __syncthreads();
    unsigned short* dst = Wt + (size_t)z * 512 * 512;
    #pragma unroll
    for (int r = ty; r < 32; r += 8)
      dst[(size_t)(n0 + r) * 512 + k0 + tx] = tile[tx][r];
  } else {
    float4 zz = {0.f, 0.f, 0.f, 0.f};
    #pragma unroll
    for (int p = 0; p < 4; ++p) ((float4*)Vsum)[p * 256 + t] = zz;
  }
}

// ---------------- QKV GEMM (bf16 out, BK=64) + fused V column sums ---------
// C[8192,1536] = A[8192,512] * Bt[1536,512]^T.
// LDS slot (row r, chunk cs) holds global k-chunk cs^(r&7) => fragment
// ds_read_b128 lands 2-way/bank (free).
__global__ __launch_bounds__(256) void gemm_qkv_kernel(
    const unsigned short* __restrict__ A, const unsigned short* __restrict__ Bt,
    unsigned short* __restrict__ C, float* __restrict__ Vsum) {
  const int N = 1536, K = 512;
  __shared__ __align__(16) unsigned short smem[16384];  // 32 KB
  unsigned short* As = smem;          // 128x64 = 8192 ush
  unsigned short* Bs = smem + 8192;
  const int t = threadIdx.x, wave = t >> 6, lane = t & 63;
  const int wr = wave >> 1, wc = wave & 1;
  const int quad = lane >> 4, l16 = lane & 15;
  const int bm = blockIdx.y * 128, bn = blockIdx.x * 128;

  const unsigned short *gA[4], *gB[4];
  #pragma unroll
  for (int p = 0; p < 4; ++p) {
    const int ci = wave * 256 + p * 64 + lane;
    const int r = ci >> 3, c = (ci & 7) ^ (r & 7);
    gA[p] = A + (size_t)(bm + r) * K + c * 8;
    gB[p] = Bt + (size_t)(bn + r) * K + c * 8;
  }

  f4v acc[4][4];
  #pragma unroll
  for (int i = 0; i < 4; ++i)
    #pragma unroll
    for (int j = 0; j < 4; ++j) {
      f4v z = {0.f, 0.f, 0.f, 0.f};
      acc[i][j] = z;
    }

  #pragma unroll
  for (int it = 0; it < 8; ++it) {
    const int kt = it * 64;
    #pragma unroll
    for (int p = 0; p < 4; ++p)
      gload_lds16(gA[p] + kt, As + wave * 2048 + p * 512);
    #pragma unroll
    for (int p = 0; p < 4; ++p)
      gload_lds16(gB[p] + kt, Bs + wave * 2048 + p * 512);
    __syncthreads();

    #pragma unroll
    for (int s = 0; s < 2; ++s) {
      s8v af[4], bf[4];
      #pragma unroll
      for (int i = 0; i < 4; ++i) {
        const int r = wr * 64 + i * 16 + l16;
        af[i] = *(const s8v*)&As[(r * 8 + ((quad + 4 * s) ^ (r & 7))) * 8];
      }
      #pragma unroll
      for (int j = 0; j < 4; ++j) {
        const int r = wc * 64 + j * 16 + l16;
        bf[j] = *(const s8v*)&Bs[(r * 8 + ((quad + 4 * s) ^ (r & 7))) * 8];
      }
      #pragma unroll
      for (int i = 0; i < 4; ++i)
        #pragma unroll
        for (int j = 0; j < 4; ++j)
          acc[i][j] = __builtin_amdgcn_mfma_f32_16x16x32_bf16(
              af[i], bf[j], acc[i][j], 0, 0, 0);
    }
    __syncthreads();
  }

  // fused V column sums (fp32 acc, quad-reduced, atomic per column)
  if (bn >= 1024) {
    const int b = bm >> 10;
    #pragma unroll
    for (int j = 0; j < 4; ++j) {
      float ps = 0.f;
      #pragma unroll
      for (int i = 0; i < 4; ++i)
        #pragma unroll
        for (int r = 0; r < 4; ++r) ps += acc[i][j][r];
      ps += __shfl_xor(ps, 16);
      ps += __shfl_xor(ps, 32);
      if (quad == 0)
        atomicAdd(&Vsum[b * 512 + (bn - 1024) + wc * 64 + j * 16 + l16], ps);
    }
  }

  // bf16 C via LDS bounce -> coalesced 16B stores
  #pragma unroll
  for (int i = 0; i < 4; ++i) {
    const int lr0 = wr * 64 + i * 16 + quad * 4;
    #pragma unroll
    for (int j = 0; j < 4; ++j) {
      const int lc = wc * 64 + j * 16 + l16;
      #pragma unroll
      for (int r = 0; r < 4; ++r)
        smem[(lr0 + r) * 128 + lc] = f2b(acc[i][j][r]);
    }
  }
  __syncthreads();
  #pragma unroll
  for (int p = 0; p < 8; ++p) {
    const int row = p * 16 + (t >> 4);
    const int ch  = t & 15;
    *(us8v*)(C + (size_t)(bm + row) * N + bn + ch * 8) =
        *(const us8v*)&smem[row * 128 + ch * 8];
  }
}

// ---------------- band attention fused with FC GEMM + residual + LN --------
// Block: 32 rows x 512 cols; 512 threads = 8 waves (2 row-groups x 4 col).
// Phase A: issue B k-tile 0 DMA, then closed-form band attention for the 32
//   rows (QKV read direct from global, L2/L3-resident), ctx written to LDS
//   bf16 in the GEMM A fragment layout (chunk ^ (row&7) swizzle).
// Phase B: BK=64 GEMM, B-only LDS double buffer, ONE barrier per iter, next
//   B tile DMA issued under the MFMA chain (1 block/CU => explicit overlap).
// LDS: 2x64KB B dbuf + 32KB ctx = 160 KB (hardware max).
#define OS 516  // f32 row stride in LDS epilogue

__global__ __launch_bounds__(512) void attn_fcln_kernel(
    const unsigned short* __restrict__ QKV,  // [8192,1536] bf16 (Q|K|V)
    const float* __restrict__ Vsum,          // [8,512]
    const unsigned short* __restrict__ Bt,   // Wfc^T [512,512] bf16
    const unsigned short* __restrict__ xb, const float* __restrict__ gamma,
    const float* __restrict__ beta, float* __restrict__ y) {
  const int K = 512;
  __shared__ __align__(16) unsigned short smem[81920];  // 160 KB exactly
  unsigned short* ctxS = smem + 65536;                  // 32x512 bf16, swizzled
  float* outS = (float*)smem;

  const int t = threadIdx.x, wave = t >> 6, lane = t & 63;
  const int bm = blockIdx.x * 32;

  // B staging: 4096 16B chunks per k-tile, 8 instrs per wave, XOR-swizzled src
  const unsigned short* gB[8];
  #pragma unroll
  for (int p = 0; p < 8; ++p) {
    const int ci = wave * 512 + p * 64 + lane;
    const int r = ci >> 3, c = (ci & 7) ^ (r & 7);
    gB[p] = Bt + (size_t)r * K + c * 8;
  }
  // k-tile 0 DMA in flight under the attention phase
  #pragma unroll
  for (int p = 0; p < 8; ++p)
    gload_lds16(gB[p], smem + wave * 4096 + p * 512);

  // ---- Phase A: band attention for rows bm..bm+31 ----
  {
    const int ql   = t >> 4;        // 0..31 local row
    const int h    = (t >> 1) & 7;  // head
    const int half = t & 1;         // 32-col half of the head
    const int b    = bm >> 10;
    const int qq   = (bm & 1023) + ql;  // row within batch
    const int co   = h * 64 + half * 32;
    const size_t rowb = (size_t)b * 1024 * 1536;
    const int qm = qq > 0 ? qq - 1 : 0;
    const int qp = qq < 1023 ? qq + 1 : 1023;
    const unsigned short* Qp  = QKV + rowb + (size_t)qq * 1536 + co;
    const unsigned short* Kp0 = QKV + rowb + (size_t)qq * 1536 + 512 + co;
    const unsigned short* Kpm = QKV + rowb + (size_t)qm * 1536 + 512 + co;
    const unsigned short* Kpp = QKV + rowb + (size_t)qp * 1536 + 512 + co;

    us8v qv[4], km[4], k0[4], kp[4];
    #pragma unroll
    for (int j = 0; j < 4; ++j) {
      qv[j] = *(const us8v*)(Qp  + j * 8);
      km[j] = *(const us8v*)(Kpm + j * 8);
      k0[j] = *(const us8v*)(Kp0 + j * 8);
      kp[j] = *(const us8v*)(Kpp + j * 8);
    }
    float pm = 0.f, p0 = 0.f, pp = 0.f;
    #pragma unroll
    for (int j = 0; j < 4; ++j)
      #pragma unroll
      for (int r = 0; r < 8; ++r) {
        const float qf = b2f(qv[j][r]);
        pm += qf * b2f(km[j][r]);
        p0 += qf * b2f(k0[j][r]);
        pp += qf * b2f(kp[j][r]);
      }
    pm += __shfl_xor(pm, 1);
    p0 += __shfl_xor(p0, 1);
    pp += __shfl_xor(pp, 1);

    const float OFF = -1e-9f;
    const float s0 = p0 * 0.125f;
    const float sm = (qq > 0)    ? pm * 0.125f : OFF;
    const float sp = (qq < 1023) ? pp * 0.125f : OFF;
    const float m  = fmaxf(fmaxf(s0, sm), fmaxf(sp, OFF));
    const float e0 = __expf(s0 - m), em = __expf(sm - m), ep = __expf(sp - m);
    const float eoff = __expf(OFF - m);
    const float inv  = 1.f / (e0 + em + ep + 1021.f * eoff);
    const float wm = (em - eoff) * inv, w0 = (e0 - eoff) * inv,
                wp = (ep - eoff) * inv, wt = eoff * inv;

    const unsigned short* Vp0 = Kp0 + 512;
    const unsigned short* Vpm = Kpm + 512;
    const unsigned short* Vpp = Kpp + 512;
    const float* vsp = Vsum + b * 512 + co;
    us8v o[4];
    #pragma unroll
    for (int jj = 0; jj < 4; ++jj) {
      const us8v a  = *(const us8v*)(Vpm + jj * 8);
      const us8v v0 = *(const us8v*)(Vp0 + jj * 8);
      const us8v c  = *(const us8v*)(Vpp + jj * 8);
      const float4 vsa = *(const float4*)&vsp[jj * 8];
      const float4 vsb = *(const float4*)&vsp[jj * 8 + 4];
      #pragma unroll
      for (int r = 0; r < 4; ++r) {
        const float vs0 = (&vsa.x)[r];
        const float vs1 = (&vsb.x)[r];
        o[jj][r]     = f2b(wt * vs0 + wm * b2f(a[r]) + w0 * b2f(v0[r]) +
                           wp * b2f(c[r]));
        o[jj][r + 4] = f2b(wt * vs1 + wm * b2f(a[r + 4]) + w0 * b2f(v0[r + 4]) +
                           wp * b2f(c[r + 4]));
      }
    }
    // swizzled ctx store; issue order rotated by h so the 8 heads of a
    // row-group hit different bank groups (~2-way instead of 8-way)
    #pragma unroll
    for (int s = 0; s < 4; ++s) {
      const int jj = (s + h) & 3;
      const int ch = (co >> 3) + jj;                     // global k-chunk
      const int slot = (ch & 56) | ((ch & 7) ^ (ql & 7));
      *(us8v*)&ctxS[ql * 512 + slot * 8] = o[jj];
    }
  }
  __syncthreads();  // ctx ready; B k-tile 0 DMA drained

  // ---- Phase B: 32x512 GEMM, A from ctxS (persistent), B double-buffered ---
  const int wrr = wave >> 2, wcc = wave & 3;
  const int quad = lane >> 4, l16 = lane & 15;

  f4v acc[8];
  #pragma unroll
  for (int j = 0; j < 8; ++j) {
    f4v z = {0.f, 0.f, 0.f, 0.f};
    acc[j] = z;
  }

  #pragma unroll
  for (int it = 0; it < 8; ++it) {
    const int cur = (it & 1) * 32768;
    const int nxt = 32768 - cur;
    const unsigned short* Bb = smem + cur;
    const int rm = wrr * 16 + l16;
    const s8v af0 =
        *(const s8v*)&ctxS[rm * 512 + (it * 8 + (quad ^ (rm & 7))) * 8];
    const s8v af1 =
        *(const s8v*)&ctxS[rm * 512 + (it * 8 + ((quad + 4) ^ (rm & 7))) * 8];
    s8v bf0[8];
    #pragma unroll
    for (int j = 0; j < 8; ++j) {
      const int n = wcc * 128 + j * 16 + l16;
      bf0[j] = *(const s8v*)&Bb[(n * 8 + (quad ^ (n & 7))) * 8];
    }
    if (it < 7) {  // DMA next B tile; runs under the MFMA chain
      const int kt = (it + 1) * 64;
      #pragma unroll
      for (int p = 0; p < 8; ++p)
        gload_lds16(gB[p] + kt, smem + nxt + wave * 4096 + p * 512);
    }
    #pragma unroll
    for (int j = 0; j < 8; ++j)
      acc[j] = __builtin_amdgcn_mfma_f32_16x16x32_bf16(af0, bf0[j], acc[j], 0, 0, 0);
    #pragma unroll
    for (int j = 0; j < 8; ++j) {
      const int n = wcc * 128 + j * 16 + l16;
      const s8v bf1 = *(const s8v*)&Bb[(n * 8 + ((quad + 4) ^ (n & 7))) * 8];
      acc[j] = __builtin_amdgcn_mfma_f32_16x16x32_bf16(af1, bf1, acc[j], 0, 0, 0);
    }
    __syncthreads();  // drains reads of cur + DMA into nxt
  }

  // acc -> LDS fp32 (overlays B buffers; all reads drained)
  #pragma unroll
  for (int j = 0; j < 8; ++j) {
    const int col = wcc * 128 + j * 16 + l16;
    const int row0 = wrr * 16 + quad * 4;
    #pragma unroll
    for (int r = 0; r < 4; ++r)
      outS[(row0 + r) * OS + col] = acc[j][r];
  }
  __syncthreads();

  // residual (bf16 xb) + LN: 16 threads per row
  const int row = t >> 4, l = t & 15;
  const size_t gbase = (size_t)(bm + row) * 512;
  float4 v[8];
  float s1 = 0.f, s2 = 0.f;
  #pragma unroll
  for (int k = 0; k < 8; ++k) {
    const int c = k * 64 + l * 4;
    const float4 a = *(const float4*)&outS[row * OS + c];
    const us4v xv = *(const us4v*)&xb[gbase + c];
    float4 w;
    w.x = a.x + b2f(xv[0]); w.y = a.y + b2f(xv[1]);
    w.z = a.z + b2f(xv[2]); w.w = a.w + b2f(xv[3]);
    v[k] = w;
    s1 += w.x + w.y + w.z + w.w;
    s2 += w.x * w.x + w.y * w.y + w.z * w.z + w.w * w.w;
  }
  #pragma unroll
  for (int m = 1; m < 16; m <<= 1) {
    s1 += __shfl_xor(s1, m);
    s2 += __shfl_xor(s2, m);
  }
  const float mu  = s1 * (1.f / 512.f);
  const float var = s2 * (1.f / 512.f) - mu * mu;
  const float rs  = rsqrtf(var + 1e-5f);
  #pragma unroll
  for (int k = 0; k < 8; ++k) {
    const int c = k * 64 + l * 4;
    const float4 g  = *(const float4*)&gamma[c];
    const float4 bb = *(const float4*)&beta[c];
    float4 o;
    o.x = (v[k].x - mu) * rs * g.x + bb.x;
    o.y = (v[k].y - mu) * rs * g.y + bb.y;
    o.z = (v[k].z - mu) * rs * g.z + bb.z;
    o.w = (v[k].w - mu) * rs * g.w + bb.w;
    *(float4*)&y[gbase + c] = o;
  }
}

// ---------------------------------------------------------------------------
extern "C" void kernel_launch(void* const* d_in, const int* in_sizes, int n_in,
                              void* d_out, int out_size, void* d_ws, size_t ws_size,
                              hipStream_t stream) {
  const float* x     = (const float*)d_in[0];
  const float* Wq    = (const float*)d_in[1];
  const float* Wk    = (const float*)d_in[2];
  const float* Wv    = (const float*)d_in[3];
  const float* Wfc   = (const float*)d_in[4];
  const float* gamma = (const float*)d_in[5];
  const float* beta  = (const float*)d_in[6];
  float* y = (float*)d_out;

  char* ws = (char*)d_ws;
  unsigned short* Wt   = (unsigned short*)(ws);              // 2 MiB
  unsigned short* xb   = (unsigned short*)(ws + 2097152);    // 8 MiB
  unsigned short* QKV  = (unsigned short*)(ws + 10485760);   // 24 MiB
  float*          Vsum = (float*)(ws + 35651584);            // 16 KiB

  conv_kernel<<<5121, 256, 0, stream>>>(x, Wq, Wk, Wv, Wfc, xb, Wt, Vsum);
  gemm_qkv_kernel<<<dim3(12, 64), 256, 0, stream>>>(xb, Wt, QKV, Vsum);
  attn_fcln_kernel<<<256, 512, 0, stream>>>(
      QKV, Vsum, Wt + (size_t)1536 * 512, xb, gamma, beta, y);
}

// Round 2
// 121.439 us; speedup vs baseline: 1.0518x; 1.0518x over previous
//
#include <hip/hip_runtime.h>
#include <math.h>

// ---------------------------------------------------------------------------
// MultiAttention, 3 launches (round-9: attn PIPELINED into the FC GEMM K-loop)
//  1) conv: x->bf16, W->bf16^T, Vsum=0
//  2) gemm_qkv: 128x128 tile, 256 thr (768 blocks = 3/CU exact), BK=64,
//     global_load_lds + XOR-swizzled source, fused V col sums (atomics)
//  3) attn_fcln: FC K-tile it (BK=64) consumes exactly head it's 64 ctx cols,
//     so band attention is computed ONE HEAD PER GEMM ITERATION, overlapped
//     with the MFMA chain (separate VALU/MFMA pipes) and the B-tile DMA.
//     No serial attention phase (R8 lesson: serial phase at 1 block/CU cost
//     ~8 us). ctx lives only in LDS (GEMM A-operand layout, XOR-swizzled);
//     kills the 16 MB ctx round-trip and the attn dispatch.
//     LDS: 2x64KB B dbuf + 32KB ctx = 160 KB (hardware max).
// NOTE (R7 lesson): grids must be integral blocks/CU — 1.5 blocks/CU tails
// and 1-block/CU mega-fusions with serial phases both regressed.
// ---------------------------------------------------------------------------

typedef short     s8v  __attribute__((ext_vector_type(8)));   // 8 bf16
typedef float     f4v  __attribute__((ext_vector_type(4)));
typedef unsigned short us4v __attribute__((ext_vector_type(4)));
typedef unsigned short us8v __attribute__((ext_vector_type(8)));

__device__ __forceinline__ unsigned short f2b(float f) {
  union { float f; unsigned int u; } v; v.f = f;
  unsigned int u = v.u;
  return (unsigned short)((u + 0x7fffu + ((u >> 16) & 1u)) >> 16);  // RNE
}
__device__ __forceinline__ float b2f(unsigned short u) {
  union { unsigned int i; float f; } v; v.i = ((unsigned int)u) << 16;
  return v.f;
}
__device__ __forceinline__ void gload_lds16(const void* g, void* l) {
  __builtin_amdgcn_global_load_lds(
      (const __attribute__((address_space(1))) void*)g,
      (__attribute__((address_space(3))) void*)l, 16, 0, 0);
}

// ---------------- conv: x->bf16, W->bf16 transposed, Vsum=0 ----------------
__global__ __launch_bounds__(256) void conv_kernel(
    const float* __restrict__ x,
    const float* __restrict__ Wq, const float* __restrict__ Wk,
    const float* __restrict__ Wv, const float* __restrict__ Wfc,
    unsigned short* __restrict__ xb, unsigned short* __restrict__ Wt,
    float* __restrict__ Vsum) {
  __shared__ unsigned short tile[32][33];
  const int bid = blockIdx.x, t = threadIdx.x;
  if (bid < 4096) {
    const int i = bid * 256 + t;
    const float4 f = ((const float4*)x)[i];
    us4v o; o[0] = f2b(f.x); o[1] = f2b(f.y); o[2] = f2b(f.z); o[3] = f2b(f.w);
    ((us4v*)xb)[i] = o;
  } else if (bid < 5120) {
    const int id = bid - 4096;
    const int z = id >> 8, rem = id & 255;
    const int bx = rem & 15, by = rem >> 4;
    const float* W = (z == 0) ? Wq : (z == 1) ? Wk : (z == 2) ? Wv : Wfc;
    const int tx = t & 31, ty = t >> 5;
    const int n0 = bx * 32, k0 = by * 32;
    #pragma unroll
    for (int r = ty; r < 32; r += 8)
      tile[r][tx] = f2b(W[(size_t)(k0 + r) * 512 + n0 + tx]);
    __syncthreads();
    unsigned short* dst = Wt + (size_t)z * 512 * 512;
    #pragma unroll
    for (int r = ty; r < 32; r += 8)
      dst[(size_t)(n0 + r) * 512 + k0 + tx] = tile[tx][r];
  } else {
    float4 zz = {0.f, 0.f, 0.f, 0.f};
    #pragma unroll
    for (int p = 0; p < 4; ++p) ((float4*)Vsum)[p * 256 + t] = zz;
  }
}

// ---------------- QKV GEMM (bf16 out, BK=64) + fused V column sums ---------
// C[8192,1536] = A[8192,512] * Bt[1536,512]^T.
// LDS slot (row r, chunk cs) holds global k-chunk cs^(r&7) => fragment
// ds_read_b128 lands 2-way/bank (free).
__global__ __launch_bounds__(256) void gemm_qkv_kernel(
    const unsigned short* __restrict__ A, const unsigned short* __restrict__ Bt,
    unsigned short* __restrict__ C, float* __restrict__ Vsum) {
  const int N = 1536, K = 512;
  __shared__ __align__(16) unsigned short smem[16384];  // 32 KB
  unsigned short* As = smem;          // 128x64 = 8192 ush
  unsigned short* Bs = smem + 8192;
  const int t = threadIdx.x, wave = t >> 6, lane = t & 63;
  const int wr = wave >> 1, wc = wave & 1;
  const int quad = lane >> 4, l16 = lane & 15;
  const int bm = blockIdx.y * 128, bn = blockIdx.x * 128;

  const unsigned short *gA[4], *gB[4];
  #pragma unroll
  for (int p = 0; p < 4; ++p) {
    const int ci = wave * 256 + p * 64 + lane;
    const int r = ci >> 3, c = (ci & 7) ^ (r & 7);
    gA[p] = A + (size_t)(bm + r) * K + c * 8;
    gB[p] = Bt + (size_t)(bn + r) * K + c * 8;
  }

  f4v acc[4][4];
  #pragma unroll
  for (int i = 0; i < 4; ++i)
    #pragma unroll
    for (int j = 0; j < 4; ++j) {
      f4v z = {0.f, 0.f, 0.f, 0.f};
      acc[i][j] = z;
    }

  #pragma unroll
  for (int it = 0; it < 8; ++it) {
    const int kt = it * 64;
    #pragma unroll
    for (int p = 0; p < 4; ++p)
      gload_lds16(gA[p] + kt, As + wave * 2048 + p * 512);
    #pragma unroll
    for (int p = 0; p < 4; ++p)
      gload_lds16(gB[p] + kt, Bs + wave * 2048 + p * 512);
    __syncthreads();

    #pragma unroll
    for (int s = 0; s < 2; ++s) {
      s8v af[4], bf[4];
      #pragma unroll
      for (int i = 0; i < 4; ++i) {
        const int r = wr * 64 + i * 16 + l16;
        af[i] = *(const s8v*)&As[(r * 8 + ((quad + 4 * s) ^ (r & 7))) * 8];
      }
      #pragma unroll
      for (int j = 0; j < 4; ++j) {
        const int r = wc * 64 + j * 16 + l16;
        bf[j] = *(const s8v*)&Bs[(r * 8 + ((quad + 4 * s) ^ (r & 7))) * 8];
      }
      #pragma unroll
      for (int i = 0; i < 4; ++i)
        #pragma unroll
        for (int j = 0; j < 4; ++j)
          acc[i][j] = __builtin_amdgcn_mfma_f32_16x16x32_bf16(
              af[i], bf[j], acc[i][j], 0, 0, 0);
    }
    __syncthreads();
  }

  // fused V column sums (fp32 acc, quad-reduced, atomic per column)
  if (bn >= 1024) {
    const int b = bm >> 10;
    #pragma unroll
    for (int j = 0; j < 4; ++j) {
      float ps = 0.f;
      #pragma unroll
      for (int i = 0; i < 4; ++i)
        #pragma unroll
        for (int r = 0; r < 4; ++r) ps += acc[i][j][r];
      ps += __shfl_xor(ps, 16);
      ps += __shfl_xor(ps, 32);
      if (quad == 0)
        atomicAdd(&Vsum[b * 512 + (bn - 1024) + wc * 64 + j * 16 + l16], ps);
    }
  }

  // bf16 C via LDS bounce -> coalesced 16B stores
  #pragma unroll
  for (int i = 0; i < 4; ++i) {
    const int lr0 = wr * 64 + i * 16 + quad * 4;
    #pragma unroll
    for (int j = 0; j < 4; ++j) {
      const int lc = wc * 64 + j * 16 + l16;
      #pragma unroll
      for (int r = 0; r < 4; ++r)
        smem[(lr0 + r) * 128 + lc] = f2b(acc[i][j][r]);
    }
  }
  __syncthreads();
  #pragma unroll
  for (int p = 0; p < 8; ++p) {
    const int row = p * 16 + (t >> 4);
    const int ch  = t & 15;
    *(us8v*)(C + (size_t)(bm + row) * N + bn + ch * 8) =
        *(const us8v*)&smem[row * 128 + ch * 8];
  }
}

// ---------------- per-head band attention helpers --------------------------
// 512 threads = 32 rows x 16 lanes; each lane owns 4 cols of head h.
__device__ __forceinline__ void attn_load(
    const unsigned short* __restrict__ QKV, const float* __restrict__ Vsum,
    size_t oq, size_t om, size_t op, int vsbase, int co,
    us4v& qv, us4v& km, us4v& k0, us4v& kp,
    us4v& vm, us4v& v0, us4v& vp, float4& vs) {
  qv = *(const us4v*)(QKV + oq + co);
  km = *(const us4v*)(QKV + om + 512 + co);
  k0 = *(const us4v*)(QKV + oq + 512 + co);
  kp = *(const us4v*)(QKV + op + 512 + co);
  vm = *(const us4v*)(QKV + om + 1024 + co);
  v0 = *(const us4v*)(QKV + oq + 1024 + co);
  vp = *(const us4v*)(QKV + op + 1024 + co);
  vs = *(const float4*)(Vsum + vsbase + co);
}

__device__ __forceinline__ void attn_compute(
    int qq, int arow, int al, int h, unsigned short* ctxS,
    us4v qv, us4v km, us4v k0, us4v kp,
    us4v vm, us4v v0, us4v vp, float4 vs) {
  float pm = 0.f, p0 = 0.f, pp = 0.f;
  #pragma unroll
  for (int r = 0; r < 4; ++r) {
    const float qf = b2f(qv[r]);
    pm += qf * b2f(km[r]);
    p0 += qf * b2f(k0[r]);
    pp += qf * b2f(kp[r]);
  }
  #pragma unroll
  for (int m = 1; m < 16; m <<= 1) {  // 16-lane butterfly: all lanes get dots
    pm += __shfl_xor(pm, m);
    p0 += __shfl_xor(p0, m);
    pp += __shfl_xor(pp, m);
  }
  const float OFF = -1e-9f;
  const float s0 = p0 * 0.125f;
  const float sm = (qq > 0)    ? pm * 0.125f : OFF;
  const float sp = (qq < 1023) ? pp * 0.125f : OFF;
  const float mx = fmaxf(fmaxf(s0, sm), fmaxf(sp, OFF));
  const float e0 = __expf(s0 - mx), em = __expf(sm - mx), ep = __expf(sp - mx);
  const float eoff = __expf(OFF - mx);
  const float inv  = 1.f / (e0 + em + ep + 1021.f * eoff);
  const float wm = (em - eoff) * inv, w0 = (e0 - eoff) * inv,
              wp = (ep - eoff) * inv, wt = eoff * inv;
  us4v o;
  const float* vsf = (const float*)&vs;
  #pragma unroll
  for (int r = 0; r < 4; ++r)
    o[r] = f2b(wt * vsf[r] + wm * b2f(vm[r]) + w0 * b2f(v0[r]) +
               wp * b2f(vp[r]));
  // GEMM A-operand swizzle: chunk ch of row arow lives at slot
  // (ch&56)|((ch&7)^(arow&7)); lane parity picks the 8B half of the chunk.
  const int ch   = h * 8 + (al >> 1);
  const int slot = (ch & 56) | ((ch & 7) ^ (arow & 7));
  *(us4v*)&ctxS[arow * 512 + slot * 8 + (al & 1) * 4] = o;
}

// ---------------- FC GEMM with in-loop attention + residual + LN -----------
// Block: 32 rows x 512 cols; 512 threads = 8 waves (2 row-groups x 4 col).
// Iter it: attn loads for head it+1 (oldest VMEM -> counted wait), ds_read
// fragments, DMA B tile it+1, MFMA chain (covers attn-load latency), head
// it+1 softmax/PV on the VALU pipe, ctx store (region disjoint from the
// head-it region the MFMAs read), ONE barrier.
#define OS 516  // f32 row stride in LDS epilogue

__global__ __launch_bounds__(512) void attn_fcln_kernel(
    const unsigned short* __restrict__ QKV,  // [8192,1536] bf16 (Q|K|V)
    const float* __restrict__ Vsum,          // [8,512]
    const unsigned short* __restrict__ Bt,   // Wfc^T [512,512] bf16
    const unsigned short* __restrict__ xb, const float* __restrict__ gamma,
    const float* __restrict__ beta, float* __restrict__ y) {
  const int K = 512;
  __shared__ __align__(16) unsigned short smem[81920];  // 160 KB exactly
  unsigned short* ctxS = smem + 65536;                  // 32x512 bf16, swizzled
  float* outS = (float*)smem;

  const int t = threadIdx.x, wave = t >> 6, lane = t & 63;
  const int bm = blockIdx.x * 32;

  // B staging: 4096 16B chunks per k-tile, 8 instrs per wave, XOR-swizzled src
  const unsigned short* gB[8];
  #pragma unroll
  for (int p = 0; p < 8; ++p) {
    const int ci = wave * 512 + p * 64 + lane;
    const int r = ci >> 3, c = (ci & 7) ^ (r & 7);
    gB[p] = Bt + (size_t)r * K + c * 8;
  }

  // attention thread geometry (same for all heads)
  const int arow = t >> 4, al = t & 15;
  const int b = bm >> 10;
  const int qq = (bm & 1023) + arow;
  const int qm = qq > 0 ? qq - 1 : 0;
  const int qp = qq < 1023 ? qq + 1 : 1023;
  const size_t rowb = (size_t)b * 1024 * 1536;
  const size_t oq = rowb + (size_t)qq * 1536;
  const size_t om = rowb + (size_t)qm * 1536;
  const size_t op = rowb + (size_t)qp * 1536;
  const int vsbase = b * 512;

  // prologue: head-0 attn loads (oldest), B tile-0 DMA, head-0 compute
  {
    us4v qv, km, k0, kp, vm, v0, vp; float4 vs;
    attn_load(QKV, Vsum, oq, om, op, vsbase, al * 4,
              qv, km, k0, kp, vm, v0, vp, vs);
    #pragma unroll
    for (int p = 0; p < 8; ++p)
      gload_lds16(gB[p], smem + wave * 4096 + p * 512);
    attn_compute(qq, arow, al, 0, ctxS, qv, km, k0, kp, vm, v0, vp, vs);
  }
  __syncthreads();  // ctx head 0 ready; B k-tile 0 drained

  // GEMM geometry
  const int wrr = wave >> 2, wcc = wave & 3;
  const int quad = lane >> 4, l16 = lane & 15;

  f4v acc[8];
  #pragma unroll
  for (int j = 0; j < 8; ++j) {
    f4v z = {0.f, 0.f, 0.f, 0.f};
    acc[j] = z;
  }

  #pragma unroll
  for (int it = 0; it < 8; ++it) {
    const int cur = (it & 1) * 32768;
    const int nxt = 32768 - cur;
    const unsigned short* Bb = smem + cur;

    // attn loads for head it+1 FIRST (oldest VMEM of the iteration)
    us4v qv, km, k0, kp, vm, v0, vp; float4 vs;
    if (it < 7)
      attn_load(QKV, Vsum, oq, om, op, vsbase, (it + 1) * 64 + al * 4,
                qv, km, k0, kp, vm, v0, vp, vs);

    const int rm = wrr * 16 + l16;
    const s8v af0 =
        *(const s8v*)&ctxS[rm * 512 + (it * 8 + (quad ^ (rm & 7))) * 8];
    const s8v af1 =
        *(const s8v*)&ctxS[rm * 512 + (it * 8 + ((quad + 4) ^ (rm & 7))) * 8];
    s8v bf0[8];
    #pragma unroll
    for (int j = 0; j < 8; ++j) {
      const int n = wcc * 128 + j * 16 + l16;
      bf0[j] = *(const s8v*)&Bb[(n * 8 + (quad ^ (n & 7))) * 8];
    }
    if (it < 7) {  // DMA next B tile; runs under the MFMA chain
      const int kt = (it + 1) * 64;
      #pragma unroll
      for (int p = 0; p < 8; ++p)
        gload_lds16(gB[p] + kt, smem + nxt + wave * 4096 + p * 512);
    }
    #pragma unroll
    for (int j = 0; j < 8; ++j)
      acc[j] = __builtin_amdgcn_mfma_f32_16x16x32_bf16(af0, bf0[j], acc[j], 0, 0, 0);
    #pragma unroll
    for (int j = 0; j < 8; ++j) {
      const int n = wcc * 128 + j * 16 + l16;
      const s8v bf1 = *(const s8v*)&Bb[(n * 8 + ((quad + 4) ^ (n & 7))) * 8];
      acc[j] = __builtin_amdgcn_mfma_f32_16x16x32_bf16(af1, bf1, acc[j], 0, 0, 0);
    }
    // head it+1 softmax/PV on the VALU pipe; writes a ctx region disjoint
    // from the head-it region the MFMAs above read
    if (it < 7)
      attn_compute(qq, arow, al, it + 1, ctxS, qv, km, k0, kp, vm, v0, vp, vs);
    __syncthreads();  // drains ctx writes + DMA into nxt
  }

  // acc -> LDS fp32 (overlays B buffers; all reads drained)
  #pragma unroll
  for (int j = 0; j < 8; ++j) {
    const int col = wcc * 128 + j * 16 + l16;
    const int row0 = wrr * 16 + quad * 4;
    #pragma unroll
    for (int r = 0; r < 4; ++r)
      outS[(row0 + r) * OS + col] = acc[j][r];
  }
  __syncthreads();

  // residual (bf16 xb) + LN: 16 threads per row
  const int row = t >> 4, l = t & 15;
  const size_t gbase = (size_t)(bm + row) * 512;
  float4 v[8];
  float s1 = 0.f, s2 = 0.f;
  #pragma unroll
  for (int k = 0; k < 8; ++k) {
    const int c = k * 64 + l * 4;
    const float4 a = *(const float4*)&outS[row * OS + c];
    const us4v xv = *(const us4v*)&xb[gbase + c];
    float4 w;
    w.x = a.x + b2f(xv[0]); w.y = a.y + b2f(xv[1]);
    w.z = a.z + b2f(xv[2]); w.w = a.w + b2f(xv[3]);
    v[k] = w;
    s1 += w.x + w.y + w.z + w.w;
    s2 += w.x * w.x + w.y * w.y + w.z * w.z + w.w * w.w;
  }
  #pragma unroll
  for (int m = 1; m < 16; m <<= 1) {
    s1 += __shfl_xor(s1, m);
    s2 += __shfl_xor(s2, m);
  }
  const float mu  = s1 * (1.f / 512.f);
  const float var = s2 * (1.f / 512.f) - mu * mu;
  const float rs  = rsqrtf(var + 1e-5f);
  #pragma unroll
  for (int k = 0; k < 8; ++k) {
    const int c = k * 64 + l * 4;
    const float4 g  = *(const float4*)&gamma[c];
    const float4 bb = *(const float4*)&beta[c];
    float4 o;
    o.x = (v[k].x - mu) * rs * g.x + bb.x;
    o.y = (v[k].y - mu) * rs * g.y + bb.y;
    o.z = (v[k].z - mu) * rs * g.z + bb.z;
    o.w = (v[k].w - mu) * rs * g.w + bb.w;
    *(float4*)&y[gbase + c] = o;
  }
}

// ---------------------------------------------------------------------------
extern "C" void kernel_launch(void* const* d_in, const int* in_sizes, int n_in,
                              void* d_out, int out_size, void* d_ws, size_t ws_size,
                              hipStream_t stream) {
  const float* x     = (const float*)d_in[0];
  const float* Wq    = (const float*)d_in[1];
  const float* Wk    = (const float*)d_in[2];
  const float* Wv    = (const float*)d_in[3];
  const float* Wfc   = (const float*)d_in[4];
  const float* gamma = (const float*)d_in[5];
  const float* beta  = (const float*)d_in[6];
  float* y = (float*)d_out;

  char* ws = (char*)d_ws;
  unsigned short* Wt   = (unsigned short*)(ws);              // 2 MiB
  unsigned short* xb   = (unsigned short*)(ws + 2097152);    // 8 MiB
  unsigned short* QKV  = (unsigned short*)(ws + 10485760);   // 24 MiB
  float*          Vsum = (float*)(ws + 35651584);            // 16 KiB

  conv_kernel<<<5121, 256, 0, stream>>>(x, Wq, Wk, Wv, Wfc, xb, Wt, Vsum);
  gemm_qkv_kernel<<<dim3(12, 64), 256, 0, stream>>>(xb, Wt, QKV, Vsum);
  attn_fcln_kernel<<<256, 512, 0, stream>>>(
      QKV, Vsum, Wt + (size_t)1536 * 512, xb, gamma, beta, y);
}

// Round 4
// 117.234 us; speedup vs baseline: 1.0896x; 1.0359x over previous
//
#include <hip/hip_runtime.h>
#include <math.h>

// ---------------------------------------------------------------------------
// MultiAttention, 3 launches (round-11: R10 with the af1[i] compile fix)
//  1) conv: x->bf16, W->bf16^T, Vsum=0
//  2) gemm_qkv: 128x384 tile, 512 thr (4x64=256 blocks = 1/CU exact), BK=64,
//     fcln-style one-barrier loop: next-tile DMA issued under the 48-MFMA
//     chain; staged bytes 192->128 MB; fused V col sums (atomics).
//  3) attn_fcln: band attention computed ONE HEAD PER GEMM ITERATION inside
//     the FC K-loop (head it == ctx cols of K-tile it), overlapped with MFMA
//     + B DMA; residual + LayerNorm epilogue. ctx lives only in LDS.
// NOTE (R7 lesson): grids must be integral blocks/CU. (R8 lesson): no serial
// phases at 1 block/CU — overlap everything inside the K-loop.
// ---------------------------------------------------------------------------

typedef short     s8v  __attribute__((ext_vector_type(8)));   // 8 bf16
typedef float     f4v  __attribute__((ext_vector_type(4)));
typedef unsigned short us4v __attribute__((ext_vector_type(4)));
typedef unsigned short us8v __attribute__((ext_vector_type(8)));

__device__ __forceinline__ unsigned short f2b(float f) {
  union { float f; unsigned int u; } v; v.f = f;
  unsigned int u = v.u;
  return (unsigned short)((u + 0x7fffu + ((u >> 16) & 1u)) >> 16);  // RNE
}
__device__ __forceinline__ float b2f(unsigned short u) {
  union { unsigned int i; float f; } v; v.i = ((unsigned int)u) << 16;
  return v.f;
}
__device__ __forceinline__ void gload_lds16(const void* g, void* l) {
  __builtin_amdgcn_global_load_lds(
      (const __attribute__((address_space(1))) void*)g,
      (__attribute__((address_space(3))) void*)l, 16, 0, 0);
}

// ---------------- conv: x->bf16, W->bf16 transposed, Vsum=0 ----------------
__global__ __launch_bounds__(256) void conv_kernel(
    const float* __restrict__ x,
    const float* __restrict__ Wq, const float* __restrict__ Wk,
    const float* __restrict__ Wv, const float* __restrict__ Wfc,
    unsigned short* __restrict__ xb, unsigned short* __restrict__ Wt,
    float* __restrict__ Vsum) {
  __shared__ unsigned short tile[32][33];
  const int bid = blockIdx.x, t = threadIdx.x;
  if (bid < 4096) {
    const int i = bid * 256 + t;
    const float4 f = ((const float4*)x)[i];
    us4v o; o[0] = f2b(f.x); o[1] = f2b(f.y); o[2] = f2b(f.z); o[3] = f2b(f.w);
    ((us4v*)xb)[i] = o;
  } else if (bid < 5120) {
    const int id = bid - 4096;
    const int z = id >> 8, rem = id & 255;
    const int bx = rem & 15, by = rem >> 4;
    const float* W = (z == 0) ? Wq : (z == 1) ? Wk : (z == 2) ? Wv : Wfc;
    const int tx = t & 31, ty = t >> 5;
    const int n0 = bx * 32, k0 = by * 32;
    #pragma unroll
    for (int r = ty; r < 32; r += 8)
      tile[r][tx] = f2b(W[(size_t)(k0 + r) * 512 + n0 + tx]);
    __syncthreads();
    unsigned short* dst = Wt + (size_t)z * 512 * 512;
    #pragma unroll
    for (int r = ty; r < 32; r += 8)
      dst[(size_t)(n0 + r) * 512 + k0 + tx] = tile[tx][r];
  } else {
    float4 zz = {0.f, 0.f, 0.f, 0.f};
    #pragma unroll
    for (int p = 0; p < 4; ++p) ((float4*)Vsum)[p * 256 + t] = zz;
  }
}

// ---------------- QKV GEMM: 128x384 tile, one-barrier pipelined loop -------
// C[8192,1536] = A[8192,512] * Bt[1536,512]^T.  512 thr = 8 waves (2 rg x
// 4 cg); wave tile 64x96 (4x6 16x16 frags). LDS slot (row r, chunk cs) holds
// global k-chunk cs^(r&7) => ds_read_b128 lands 2-way/bank (free).
// Per iter: frag reads -> next-tile DMA (under MFMA) -> 48 MFMA -> 1 barrier.
__global__ __launch_bounds__(512, 2) void gemm_qkv_kernel(
    const unsigned short* __restrict__ A, const unsigned short* __restrict__ Bt,
    unsigned short* __restrict__ C, float* __restrict__ Vsum) {
  const int N = 1536, K = 512;
  // buffer: A 128x64 = 8192 ush, B 384x64 = 24576 ush -> 32768 ush; x2=128 KB
  __shared__ __align__(16) unsigned short smem[65536];
  const int t = threadIdx.x, wave = t >> 6, lane = t & 63;
  const int wrr = wave >> 2, wcc = wave & 3;
  const int quad = lane >> 4, l16 = lane & 15;
  const int bm = blockIdx.y * 128, bn = blockIdx.x * 384;

  const unsigned short* gA[2];
  #pragma unroll
  for (int p = 0; p < 2; ++p) {
    const int ci = wave * 128 + p * 64 + lane;
    const int r = ci >> 3, c = (ci & 7) ^ (r & 7);
    gA[p] = A + (size_t)(bm + r) * K + c * 8;
  }
  const unsigned short* gB[6];
  #pragma unroll
  for (int p = 0; p < 6; ++p) {
    const int ci = wave * 384 + p * 64 + lane;
    const int r = ci >> 3, c = (ci & 7) ^ (r & 7);
    gB[p] = Bt + (size_t)(bn + r) * K + c * 8;
  }

  f4v acc[4][6];
  #pragma unroll
  for (int i = 0; i < 4; ++i)
    #pragma unroll
    for (int j = 0; j < 6; ++j) {
      f4v z = {0.f, 0.f, 0.f, 0.f};
      acc[i][j] = z;
    }

  // prologue: stage k-tile 0 into buffer 0
  #pragma unroll
  for (int p = 0; p < 2; ++p)
    gload_lds16(gA[p], smem + (wave * 128 + p * 64) * 8);
  #pragma unroll
  for (int p = 0; p < 6; ++p)
    gload_lds16(gB[p], smem + 8192 + (wave * 384 + p * 64) * 8);
  __syncthreads();

  #pragma unroll
  for (int it = 0; it < 8; ++it) {
    const int cur = (it & 1) * 32768;
    const int nxt = 32768 - cur;
    const unsigned short* Ab = smem + cur;
    const unsigned short* Bb = smem + cur + 8192;

    s8v af0[4], af1[4];
    #pragma unroll
    for (int i = 0; i < 4; ++i) {
      const int r = wrr * 64 + i * 16 + l16;
      af0[i] = *(const s8v*)&Ab[(r * 8 + (quad ^ (r & 7))) * 8];
      af1[i] = *(const s8v*)&Ab[(r * 8 + ((quad + 4) ^ (r & 7))) * 8];
    }
    s8v bf0[6];
    #pragma unroll
    for (int j = 0; j < 6; ++j) {
      const int n = wcc * 96 + j * 16 + l16;
      bf0[j] = *(const s8v*)&Bb[(n * 8 + (quad ^ (n & 7))) * 8];
    }
    if (it < 7) {  // DMA next tile; runs under the MFMA chain
      const int kt = (it + 1) * 64;
      #pragma unroll
      for (int p = 0; p < 2; ++p)
        gload_lds16(gA[p] + kt, smem + nxt + (wave * 128 + p * 64) * 8);
      #pragma unroll
      for (int p = 0; p < 6; ++p)
        gload_lds16(gB[p] + kt, smem + nxt + 8192 + (wave * 384 + p * 64) * 8);
    }
    #pragma unroll
    for (int i = 0; i < 4; ++i)
      #pragma unroll
      for (int j = 0; j < 6; ++j)
        acc[i][j] = __builtin_amdgcn_mfma_f32_16x16x32_bf16(
            af0[i], bf0[j], acc[i][j], 0, 0, 0);
    #pragma unroll
    for (int j = 0; j < 6; ++j) {
      const int n = wcc * 96 + j * 16 + l16;
      const s8v bf1 = *(const s8v*)&Bb[(n * 8 + ((quad + 4) ^ (n & 7))) * 8];
      #pragma unroll
      for (int i = 0; i < 4; ++i)
        acc[i][j] = __builtin_amdgcn_mfma_f32_16x16x32_bf16(
            af1[i], bf1, acc[i][j], 0, 0, 0);
    }
    __syncthreads();  // drains reads of cur + DMA into nxt
  }

  // fused V column sums (fp32 acc, quad-reduced, atomic per column)
  {
    const int b = bm >> 10;
    #pragma unroll
    for (int j = 0; j < 6; ++j) {
      const int gc = bn + wcc * 96 + j * 16 + l16;
      float ps = 0.f;
      #pragma unroll
      for (int i = 0; i < 4; ++i)
        #pragma unroll
        for (int r = 0; r < 4; ++r) ps += acc[i][j][r];
      ps += __shfl_xor(ps, 16);
      ps += __shfl_xor(ps, 32);
      if (quad == 0 && gc >= 1024)
        atomicAdd(&Vsum[b * 512 + gc - 1024], ps);
    }
  }

  // bf16 C via LDS bounce (stride 392 breaks quad-conflicts) -> 16B stores
  #pragma unroll
  for (int i = 0; i < 4; ++i) {
    const int lr0 = wrr * 64 + i * 16 + quad * 4;
    #pragma unroll
    for (int j = 0; j < 6; ++j) {
      const int lc = wcc * 96 + j * 16 + l16;
      #pragma unroll
      for (int r = 0; r < 4; ++r)
        smem[(lr0 + r) * 392 + lc] = f2b(acc[i][j][r]);
    }
  }
  __syncthreads();
  #pragma unroll
  for (int p = 0; p < 12; ++p) {
    const int row = t >> 2;            // 0..127
    const int ch  = p * 4 + (t & 3);   // 0..47 (48 x 16B per row)
    *(us8v*)(C + (size_t)(bm + row) * N + bn + ch * 8) =
        *(const us8v*)&smem[row * 392 + ch * 8];
  }
}

// ---------------- per-head band attention helpers --------------------------
// 512 threads = 32 rows x 16 lanes; each lane owns 4 cols of head h.
__device__ __forceinline__ void attn_load(
    const unsigned short* __restrict__ QKV, const float* __restrict__ Vsum,
    size_t oq, size_t om, size_t op, int vsbase, int co,
    us4v& qv, us4v& km, us4v& k0, us4v& kp,
    us4v& vm, us4v& v0, us4v& vp, float4& vs) {
  qv = *(const us4v*)(QKV + oq + co);
  km = *(const us4v*)(QKV + om + 512 + co);
  k0 = *(const us4v*)(QKV + oq + 512 + co);
  kp = *(const us4v*)(QKV + op + 512 + co);
  vm = *(const us4v*)(QKV + om + 1024 + co);
  v0 = *(const us4v*)(QKV + oq + 1024 + co);
  vp = *(const us4v*)(QKV + op + 1024 + co);
  vs = *(const float4*)(Vsum + vsbase + co);
}

__device__ __forceinline__ void attn_compute(
    int qq, int arow, int al, int h, unsigned short* ctxS,
    us4v qv, us4v km, us4v k0, us4v kp,
    us4v vm, us4v v0, us4v vp, float4 vs) {
  float pm = 0.f, p0 = 0.f, pp = 0.f;
  #pragma unroll
  for (int r = 0; r < 4; ++r) {
    const float qf = b2f(qv[r]);
    pm += qf * b2f(km[r]);
    p0 += qf * b2f(k0[r]);
    pp += qf * b2f(kp[r]);
  }
  #pragma unroll
  for (int m = 1; m < 16; m <<= 1) {  // 16-lane butterfly: all lanes get dots
    pm += __shfl_xor(pm, m);
    p0 += __shfl_xor(p0, m);
    pp += __shfl_xor(pp, m);
  }
  const float OFF = -1e-9f;
  const float s0 = p0 * 0.125f;
  const float sm = (qq > 0)    ? pm * 0.125f : OFF;
  const float sp = (qq < 1023) ? pp * 0.125f : OFF;
  const float mx = fmaxf(fmaxf(s0, sm), fmaxf(sp, OFF));
  const float e0 = __expf(s0 - mx), em = __expf(sm - mx), ep = __expf(sp - mx);
  const float eoff = __expf(OFF - mx);
  const float inv  = 1.f / (e0 + em + ep + 1021.f * eoff);
  const float wm = (em - eoff) * inv, w0 = (e0 - eoff) * inv,
              wp = (ep - eoff) * inv, wt = eoff * inv;
  us4v o;
  const float* vsf = (const float*)&vs;
  #pragma unroll
  for (int r = 0; r < 4; ++r)
    o[r] = f2b(wt * vsf[r] + wm * b2f(vm[r]) + w0 * b2f(v0[r]) +
               wp * b2f(vp[r]));
  // GEMM A-operand swizzle: chunk ch of row arow lives at slot
  // (ch&56)|((ch&7)^(arow&7)); lane parity picks the 8B half of the chunk.
  const int ch   = h * 8 + (al >> 1);
  const int slot = (ch & 56) | ((ch & 7) ^ (arow & 7));
  *(us4v*)&ctxS[arow * 512 + slot * 8 + (al & 1) * 4] = o;
}

// ---------------- FC GEMM with in-loop attention + residual + LN -----------
// Block: 32 rows x 512 cols; 512 threads = 8 waves (2 row-groups x 4 col).
// Iter it: attn loads for head it+1 (oldest VMEM -> counted wait), ds_read
// fragments, DMA B tile it+1, MFMA chain (covers attn-load latency), head
// it+1 softmax/PV on the VALU pipe, ctx store (region disjoint from the
// head-it region the MFMAs read), ONE barrier.
#define OS 516  // f32 row stride in LDS epilogue

__global__ __launch_bounds__(512) void attn_fcln_kernel(
    const unsigned short* __restrict__ QKV,  // [8192,1536] bf16 (Q|K|V)
    const float* __restrict__ Vsum,          // [8,512]
    const unsigned short* __restrict__ Bt,   // Wfc^T [512,512] bf16
    const unsigned short* __restrict__ xb, const float* __restrict__ gamma,
    const float* __restrict__ beta, float* __restrict__ y) {
  const int K = 512;
  __shared__ __align__(16) unsigned short smem[81920];  // 160 KB exactly
  unsigned short* ctxS = smem + 65536;                  // 32x512 bf16, swizzled
  float* outS = (float*)smem;

  const int t = threadIdx.x, wave = t >> 6, lane = t & 63;
  const int bm = blockIdx.x * 32;

  // B staging: 4096 16B chunks per k-tile, 8 instrs per wave, XOR-swizzled src
  const unsigned short* gB[8];
  #pragma unroll
  for (int p = 0; p < 8; ++p) {
    const int ci = wave * 512 + p * 64 + lane;
    const int r = ci >> 3, c = (ci & 7) ^ (r & 7);
    gB[p] = Bt + (size_t)r * K + c * 8;
  }

  // attention thread geometry (same for all heads)
  const int arow = t >> 4, al = t & 15;
  const int b = bm >> 10;
  const int qq = (bm & 1023) + arow;
  const int qm = qq > 0 ? qq - 1 : 0;
  const int qp = qq < 1023 ? qq + 1 : 1023;
  const size_t rowb = (size_t)b * 1024 * 1536;
  const size_t oq = rowb + (size_t)qq * 1536;
  const size_t om = rowb + (size_t)qm * 1536;
  const size_t op = rowb + (size_t)qp * 1536;
  const int vsbase = b * 512;

  // prologue: head-0 attn loads (oldest), B tile-0 DMA, head-0 compute
  {
    us4v qv, km, k0, kp, vm, v0, vp; float4 vs;
    attn_load(QKV, Vsum, oq, om, op, vsbase, al * 4,
              qv, km, k0, kp, vm, v0, vp, vs);
    #pragma unroll
    for (int p = 0; p < 8; ++p)
      gload_lds16(gB[p], smem + wave * 4096 + p * 512);
    attn_compute(qq, arow, al, 0, ctxS, qv, km, k0, kp, vm, v0, vp, vs);
  }
  __syncthreads();  // ctx head 0 ready; B k-tile 0 drained

  // GEMM geometry
  const int wrr = wave >> 2, wcc = wave & 3;
  const int quad = lane >> 4, l16 = lane & 15;

  f4v acc[8];
  #pragma unroll
  for (int j = 0; j < 8; ++j) {
    f4v z = {0.f, 0.f, 0.f, 0.f};
    acc[j] = z;
  }

  #pragma unroll
  for (int it = 0; it < 8; ++it) {
    const int cur = (it & 1) * 32768;
    const int nxt = 32768 - cur;
    const unsigned short* Bb = smem + cur;

    // attn loads for head it+1 FIRST (oldest VMEM of the iteration)
    us4v qv, km, k0, kp, vm, v0, vp; float4 vs;
    if (it < 7)
      attn_load(QKV, Vsum, oq, om, op, vsbase, (it + 1) * 64 + al * 4,
                qv, km, k0, kp, vm, v0, vp, vs);

    const int rm = wrr * 16 + l16;
    const s8v af0 =
        *(const s8v*)&ctxS[rm * 512 + (it * 8 + (quad ^ (rm & 7))) * 8];
    const s8v af1 =
        *(const s8v*)&ctxS[rm * 512 + (it * 8 + ((quad + 4) ^ (rm & 7))) * 8];
    s8v bf0[8];
    #pragma unroll
    for (int j = 0; j < 8; ++j) {
      const int n = wcc * 128 + j * 16 + l16;
      bf0[j] = *(const s8v*)&Bb[(n * 8 + (quad ^ (n & 7))) * 8];
    }
    if (it < 7) {  // DMA next B tile; runs under the MFMA chain
      const int kt = (it + 1) * 64;
      #pragma unroll
      for (int p = 0; p < 8; ++p)
        gload_lds16(gB[p] + kt, smem + nxt + wave * 4096 + p * 512);
    }
    #pragma unroll
    for (int j = 0; j < 8; ++j)
      acc[j] = __builtin_amdgcn_mfma_f32_16x16x32_bf16(af0, bf0[j], acc[j], 0, 0, 0);
    #pragma unroll
    for (int j = 0; j < 8; ++j) {
      const int n = wcc * 128 + j * 16 + l16;
      const s8v bf1 = *(const s8v*)&Bb[(n * 8 + ((quad + 4) ^ (n & 7))) * 8];
      acc[j] = __builtin_amdgcn_mfma_f32_16x16x32_bf16(af1, bf1, acc[j], 0, 0, 0);
    }
    // head it+1 softmax/PV on the VALU pipe; writes a ctx region disjoint
    // from the head-it region the MFMAs above read
    if (it < 7)
      attn_compute(qq, arow, al, it + 1, ctxS, qv, km, k0, kp, vm, v0, vp, vs);
    __syncthreads();  // drains ctx writes + DMA into nxt
  }

  // acc -> LDS fp32 (overlays B buffers; all reads drained)
  #pragma unroll
  for (int j = 0; j < 8; ++j) {
    const int col = wcc * 128 + j * 16 + l16;
    const int row0 = wrr * 16 + quad * 4;
    #pragma unroll
    for (int r = 0; r < 4; ++r)
      outS[(row0 + r) * OS + col] = acc[j][r];
  }
  __syncthreads();

  // residual (bf16 xb) + LN: 16 threads per row
  const int row = t >> 4, l = t & 15;
  const size_t gbase = (size_t)(bm + row) * 512;
  float4 v[8];
  float s1 = 0.f, s2 = 0.f;
  #pragma unroll
  for (int k = 0; k < 8; ++k) {
    const int c = k * 64 + l * 4;
    const float4 a = *(const float4*)&outS[row * OS + c];
    const us4v xv = *(const us4v*)&xb[gbase + c];
    float4 w;
    w.x = a.x + b2f(xv[0]); w.y = a.y + b2f(xv[1]);
    w.z = a.z + b2f(xv[2]); w.w = a.w + b2f(xv[3]);
    v[k] = w;
    s1 += w.x + w.y + w.z + w.w;
    s2 += w.x * w.x + w.y * w.y + w.z * w.z + w.w * w.w;
  }
  #pragma unroll
  for (int m = 1; m < 16; m <<= 1) {
    s1 += __shfl_xor(s1, m);
    s2 += __shfl_xor(s2, m);
  }
  const float mu  = s1 * (1.f / 512.f);
  const float var = s2 * (1.f / 512.f) - mu * mu;
  const float rs  = rsqrtf(var + 1e-5f);
  #pragma unroll
  for (int k = 0; k < 8; ++k) {
    const int c = k * 64 + l * 4;
    const float4 g  = *(const float4*)&gamma[c];
    const float4 bb = *(const float4*)&beta[c];
    float4 o;
    o.x = (v[k].x - mu) * rs * g.x + bb.x;
    o.y = (v[k].y - mu) * rs * g.y + bb.y;
    o.z = (v[k].z - mu) * rs * g.z + bb.z;
    o.w = (v[k].w - mu) * rs * g.w + bb.w;
    *(float4*)&y[gbase + c] = o;
  }
}

// ---------------------------------------------------------------------------
extern "C" void kernel_launch(void* const* d_in, const int* in_sizes, int n_in,
                              void* d_out, int out_size, void* d_ws, size_t ws_size,
                              hipStream_t stream) {
  const float* x     = (const float*)d_in[0];
  const float* Wq    = (const float*)d_in[1];
  const float* Wk    = (const float*)d_in[2];
  const float* Wv    = (const float*)d_in[3];
  const float* Wfc   = (const float*)d_in[4];
  const float* gamma = (const float*)d_in[5];
  const float* beta  = (const float*)d_in[6];
  float* y = (float*)d_out;

  char* ws = (char*)d_ws;
  unsigned short* Wt   = (unsigned short*)(ws);              // 2 MiB
  unsigned short* xb   = (unsigned short*)(ws + 2097152);    // 8 MiB
  unsigned short* QKV  = (unsigned short*)(ws + 10485760);   // 24 MiB
  float*          Vsum = (float*)(ws + 35651584);            // 16 KiB

  conv_kernel<<<5121, 256, 0, stream>>>(x, Wq, Wk, Wv, Wfc, xb, Wt, Vsum);
  gemm_qkv_kernel<<<dim3(4, 64), 512, 0, stream>>>(xb, Wt, QKV, Vsum);
  attn_fcln_kernel<<<256, 512, 0, stream>>>(
      QKV, Vsum, Wt + (size_t)1536 * 512, xb, gamma, beta, y);
}